// Round 8
// baseline (398.743 us; speedup 1.0000x reference)
//
#include <hip/hip_runtime.h>
#include <math.h>

#define BATCH 128

// ============================================================================
// Layer 1 (fused transpose + conv + select + pool):
// x [128][3][2048] -> X2 [1024][8][128]  (batch-minor)
// ============================================================================
__global__ __launch_bounds__(256) void l1_kernel(
    const float* __restrict__ x, const float* __restrict__ W,
    const float* __restrict__ bias, const int* __restrict__ sel,
    float* __restrict__ Xout)
{
    __shared__ float tile[3][64][65];   // [c][n_local][b_local]
    __shared__ float wl[72];
    __shared__ float bl[24];
    int tid = threadIdx.x;
    int n0 = blockIdx.x * 64;
    int b0 = blockIdx.y * 64;
    if (tid < 72) wl[tid] = W[tid];
    if (tid >= 128 && tid < 152) bl[tid - 128] = bias[tid - 128];

    int ln = tid & 63;
    int bg = tid >> 6;
#pragma unroll
    for (int c = 0; c < 3; ++c)
#pragma unroll
        for (int j = 0; j < 16; ++j) {
            int bloc = bg * 16 + j;
            tile[c][ln][bloc] = x[(size_t)(b0 + bloc) * 6144 + c * 2048 + n0 + ln];
        }
    __syncthreads();

    for (int pp = 0; pp < 8; ++pp) {
        int p  = bg * 8 + pp;
        int ng = n0 + 2 * p;
        int s0 = sel[ng];
        int s1 = sel[ng + 1];
        float xa0 = tile[0][2*p][ln],   xa1 = tile[1][2*p][ln],   xa2 = tile[2][2*p][ln];
        float xb0 = tile[0][2*p+1][ln], xb1 = tile[1][2*p+1][ln], xb2 = tile[2][2*p+1][ln];
        int npair = (n0 >> 1) + p;
#pragma unroll
        for (int f = 0; f < 8; ++f) {
            int r0 = f * 3 + s0, r1 = f * 3 + s1;
            float z0 = fmaf(wl[r0*3+2], xa2, fmaf(wl[r0*3+1], xa1, fmaf(wl[r0*3+0], xa0, bl[r0])));
            float z1 = fmaf(wl[r1*3+2], xb2, fmaf(wl[r1*3+1], xb1, fmaf(wl[r1*3+0], xb0, bl[r1])));
            Xout[((size_t)npair * 8 + f) * 128 + b0 + ln] = fmaxf(fmaxf(z0, z1), 0.f);
        }
    }
}

// ============================================================================
// Layer 2 (CIN=8, CF=32): small-K special case, W preloaded to registers.
// X [1024][8][128] -> Xout [512][32][128]. 1 wave/block, lane owns b float2.
// ============================================================================
__global__ __launch_bounds__(64) void l2_kernel(
    const float* __restrict__ X, const float* __restrict__ W,
    const float* __restrict__ bias, const int* __restrict__ sel,
    float* __restrict__ Xout)
{
    const int lane = threadIdx.x;
    const int n  = blockIdx.x;
    const int f0 = blockIdx.y * 4;
    const int s0 = __builtin_amdgcn_readfirstlane(sel[2 * n]);
    const int s1 = __builtin_amdgcn_readfirstlane(sel[2 * n + 1]);

    float4 wa[4][2], wb[4][2];
#pragma unroll
    for (int t = 0; t < 4; ++t) {
        const float* r0 = W + (size_t)((f0 + t) * 3 + s0) * 8;
        const float* r1 = W + (size_t)((f0 + t) * 3 + s1) * 8;
        wa[t][0] = *(const float4*)r0;  wa[t][1] = *(const float4*)(r0 + 4);
        wb[t][0] = *(const float4*)r1;  wb[t][1] = *(const float4*)(r1 + 4);
    }

    const float* xp0 = X + (size_t)(2 * n) * 8 * 128 + 2 * lane;
    const float* xp1 = xp0 + 8 * 128;

    float2 acc0[4], acc1[4];
#pragma unroll
    for (int t = 0; t < 4; ++t) { acc0[t] = make_float2(0.f,0.f); acc1[t] = make_float2(0.f,0.f); }

#pragma unroll
    for (int k = 0; k < 8; ++k) {
        float2 xa = *(const float2*)(xp0 + k * 128);
        float2 xb = *(const float2*)(xp1 + k * 128);
#pragma unroll
        for (int t = 0; t < 4; ++t) {
            float wva = (k < 4) ? ((const float*)&wa[t][0])[k] : ((const float*)&wa[t][1])[k-4];
            float wvb = (k < 4) ? ((const float*)&wb[t][0])[k] : ((const float*)&wb[t][1])[k-4];
            acc0[t].x = fmaf(wva, xa.x, acc0[t].x);
            acc0[t].y = fmaf(wva, xa.y, acc0[t].y);
            acc1[t].x = fmaf(wvb, xb.x, acc1[t].x);
            acc1[t].y = fmaf(wvb, xb.y, acc1[t].y);
        }
    }

#pragma unroll
    for (int t = 0; t < 4; ++t) {
        int f = f0 + t;
        float bi0 = bias[f * 3 + s0];
        float bi1 = bias[f * 3 + s1];
        float2 v;
        v.x = fmaxf(fmaxf(acc0[t].x + bi0, acc1[t].x + bi1), 0.f);
        v.y = fmaxf(fmaxf(acc0[t].y + bi0, acc1[t].y + bi1), 0.f);
        *(float2*)(Xout + ((size_t)n * 32 + f) * 128 + 2 * lane) = v;
    }
}

// ============================================================================
// tile2: layers 3..11, batch-minor.
//  X [2*NP][CIN][128] -> Xout [NP][CF][128]
//  Block = FW (f-split) x KW (k-split) waves; lane owns batch float2, both pos.
//  X chunks (BK=32 k x 128 b x 2 pos = 32 KB) double-buffered in LDS with
//  register prefetch, ONE barrier per chunk. W read straight from global with
//  all-SGPR addresses (readfirstlane'd) -> scalar s_load path, no LDS, no VMEM.
//  Inner loop per k: 2 ds_read_b64 + 32 fma  -> VALU-bound at >=4 waves/SIMD.
//  K-split partials tree-reduced through the X LDS buffer.
// ============================================================================
template<int CIN, int CF, int NP, int FW, int KW>
__global__ __launch_bounds__(64 * FW * KW) void tile2_kernel(
    const float* __restrict__ X,
    const float* __restrict__ W,
    const float* __restrict__ bias,
    const int*   __restrict__ sel,
    float* __restrict__ Xout)
{
    constexpr int TF      = 8;
    constexpr int BK      = 32;
    constexpr int NW      = FW * KW;
    constexpr int NTHR    = 64 * NW;
    constexpr int FBLK    = FW * TF;
    constexpr int KSUB    = BK / KW;
    constexpr int NCHUNK  = CIN / BK;
    constexpr int XBUF    = (NCHUNK > 1) ? 2 : 1;
    constexpr int CHUNK_F = 2 * BK * 128;              // 8192 floats = 32 KB
    constexpr int XPT     = (CHUNK_F / 4) / NTHR;      // float4 per thread
    static_assert(KSUB >= 4, "need >=4 k per wave per chunk");
    static_assert((CHUNK_F / 4) % NTHR == 0, "stage divisibility");
    static_assert(FW * (KW / 2) * 1024 * 2 <= XBUF * CHUNK_F, "reduce scratch fits");

    __shared__ float Xl[XBUF * CHUNK_F];

    const int tid  = threadIdx.x;
    const int lane = tid & 63;
    const int wv   = tid >> 6;
    const int kw   = __builtin_amdgcn_readfirstlane(wv % KW);
    const int fw   = __builtin_amdgcn_readfirstlane(wv / KW);
    const int n    = blockIdx.x;
    const int f0   = blockIdx.y * FBLK + fw * TF;

    const int s0 = __builtin_amdgcn_readfirstlane(sel[2 * n]);
    const int s1 = __builtin_amdgcn_readfirstlane(sel[2 * n + 1]);

    const float* w0p  = W + (size_t)(f0 * 3 + s0) * CIN;
    const float* w1p  = W + (size_t)(f0 * 3 + s1) * CIN;
    const float* xsrc = X + (size_t)(2 * n) * CIN * 128;

    float2 acc0[TF], acc1[TF];
#pragma unroll
    for (int t = 0; t < TF; ++t) { acc0[t] = make_float2(0.f,0.f); acc1[t] = make_float2(0.f,0.f); }

    float4 pf[XPT];
    // prefetch chunk 0
#pragma unroll
    for (int i = 0; i < XPT; ++i) {
        int v = i * NTHR + tid;
        int col4 = v & 31;
        int kk   = (v >> 5) & (BK - 1);
        int p    = v / (32 * BK);
        pf[i] = *(const float4*)(xsrc + ((size_t)(p * CIN + kk)) * 128 + 4 * col4);
    }

    for (int c = 0; c < NCHUNK; ++c) {
        // write prefetched chunk c into its buffer
        float* dst = Xl + (c & (XBUF - 1)) * CHUNK_F;
#pragma unroll
        for (int i = 0; i < XPT; ++i)
            *(float4*)(dst + (size_t)(i * NTHR + tid) * 4) = pf[i];
        __syncthreads();

        // issue prefetch of chunk c+1 (loads in flight during compute)
        if (c + 1 < NCHUNK) {
#pragma unroll
            for (int i = 0; i < XPT; ++i) {
                int v = i * NTHR + tid;
                int col4 = v & 31;
                int kk   = (v >> 5) & (BK - 1);
                int p    = v / (32 * BK);
                pf[i] = *(const float4*)(xsrc + ((size_t)(p * CIN + (c + 1) * BK + kk)) * 128 + 4 * col4);
            }
        }

        // compute chunk c: wave kw covers k in [kw*KSUB, (kw+1)*KSUB)
        const float* buf = Xl + (c & (XBUF - 1)) * CHUNK_F;
        const int kbase = kw * KSUB;
#pragma unroll
        for (int kq = 0; kq < KSUB; kq += 4) {
            const int kg = c * BK + kbase + kq;   // global k of this 4-group
            float4 wa4[TF], wb4[TF];
#pragma unroll
            for (int t = 0; t < TF; ++t) {
                wa4[t] = *(const float4*)(w0p + (size_t)(3 * t) * CIN + kg);
                wb4[t] = *(const float4*)(w1p + (size_t)(3 * t) * CIN + kg);
            }
#pragma unroll
            for (int j = 0; j < 4; ++j) {
                const int kl = kbase + kq + j;
                float2 xa = *(const float2*)&buf[(size_t)kl * 128 + 2 * lane];
                float2 xb = *(const float2*)&buf[(size_t)(BK + kl) * 128 + 2 * lane];
#pragma unroll
                for (int t = 0; t < TF; ++t) {
                    float w0v = ((const float*)&wa4[t])[j];
                    float w1v = ((const float*)&wb4[t])[j];
                    acc0[t].x = fmaf(w0v, xa.x, acc0[t].x);
                    acc0[t].y = fmaf(w0v, xa.y, acc0[t].y);
                    acc1[t].x = fmaf(w1v, xb.x, acc1[t].x);
                    acc1[t].y = fmaf(w1v, xb.y, acc1[t].y);
                }
            }
        }
        __syncthreads();
    }

    // ---- tree-reduce k-split partials through Xl scratch ----
    if constexpr (KW > 1) {
        float2* S = (float2*)Xl;
        for (int h = KW / 2; h >= 1; h >>= 1) {
            __syncthreads();
            if (kw >= h && kw < 2 * h) {
                int slot = fw * h + (kw - h);
                float2* d2 = S + (size_t)slot * 1024 + lane;
#pragma unroll
                for (int t = 0; t < TF; ++t) {
                    d2[t * 64]        = acc0[t];
                    d2[(TF + t) * 64] = acc1[t];
                }
            }
            __syncthreads();
            if (kw < h) {
                const float2* s2 = S + (size_t)(fw * h + kw) * 1024 + lane;
#pragma unroll
                for (int t = 0; t < TF; ++t) {
                    float2 a = s2[t * 64];
                    float2 b = s2[(TF + t) * 64];
                    acc0[t].x += a.x; acc0[t].y += a.y;
                    acc1[t].x += b.x; acc1[t].y += b.y;
                }
            }
        }
    }

    // ---- epilogue: bias + relu + maxpool, coalesced float2 store ----
    if (kw == 0) {
#pragma unroll
        for (int t = 0; t < TF; ++t) {
            int f = f0 + t;
            float bi0 = bias[f * 3 + s0];
            float bi1 = bias[f * 3 + s1];
            float2 v;
            v.x = fmaxf(fmaxf(acc0[t].x + bi0, acc1[t].x + bi1), 0.f);
            v.y = fmaxf(fmaxf(acc0[t].y + bi0, acc1[t].y + bi1), 0.f);
            *(float2*)(Xout + ((size_t)n * CF + f) * 128 + 2 * lane) = v;
        }
    }
}

// ============================================================================
// FC head: h batch-minor [1024][128]; out [128][16] log-softmax
// ============================================================================
__global__ __launch_bounds__(256) void fc_logsoftmax_kernel(
    const float* __restrict__ h, const float* __restrict__ fcW,
    const float* __restrict__ fcb, float* __restrict__ out)
{
    int b   = blockIdx.x;
    int tid = threadIdx.x;
    int k     = tid & 15;
    int chunk = tid >> 4;

    const float* __restrict__ wk = fcW + (size_t)k * 1024;

    float partial = 0.0f;
    int j0 = chunk * 64;
#pragma unroll 8
    for (int j = 0; j < 64; ++j)
        partial = fmaf(h[(size_t)(j0 + j) * 128 + b], wk[j0 + j], partial);

    __shared__ float red[16][17];
    red[chunk][k] = partial;
    __syncthreads();

    __shared__ float logits[16];
    if (tid < 16) {
        float s = fcb[tid];
#pragma unroll
        for (int c = 0; c < 16; ++c) s += red[c][tid];
        logits[tid] = s;
    }
    __syncthreads();

    if (tid < 16) {
        float mx = -INFINITY;
#pragma unroll
        for (int kk = 0; kk < 16; ++kk) mx = fmaxf(mx, logits[kk]);
        float se = 0.0f;
#pragma unroll
        for (int kk = 0; kk < 16; ++kk) se += expf(logits[kk] - mx);
        out[b * 16 + tid] = logits[tid] - mx - logf(se);
    }
}

// ============================================================================
extern "C" void kernel_launch(void* const* d_in, const int* in_sizes, int n_in,
                              void* d_out, int out_size, void* d_ws, size_t ws_size,
                              hipStream_t stream)
{
    const float* x   = (const float*)d_in[0];
    const float* fcW = (const float*)d_in[34];
    const float* fcb = (const float*)d_in[35];

    float* buf0 = (float*)d_ws;
    float* buf1 = (float*)d_ws + (2u * 1024u * 1024u);   // 8 MB slots

#define WL(i) (const float*)d_in[1 + 3 * (i)]
#define BL(i) (const float*)d_in[2 + 3 * (i)]
#define SL(i) (const int*)  d_in[3 + 3 * (i)]

    // L1: x -> buf0  [1024][8][128]
    l1_kernel<<<dim3(32, 2), 256, 0, stream>>>(x, WL(0), BL(0), SL(0), buf0);
    // L2: -> [512][32][128]
    l2_kernel<<<dim3(512, 8), 64, 0, stream>>>(buf0, WL(1), BL(1), SL(1), buf1);

    // L3: -> [256][64][128]   FW=2 KW=2: 1024 blocks x 256 thr
    tile2_kernel<32, 64, 256, 2, 2><<<dim3(256, 4), 256, 0, stream>>>(buf1, WL(2), BL(2), SL(2), buf0);
    // L4: -> [128][64][128]   FW=2 KW=2: 512 blocks x 256 thr
    tile2_kernel<64, 64, 128, 2, 2><<<dim3(128, 4), 256, 0, stream>>>(buf0, WL(3), BL(3), SL(3), buf1);
    // L5: -> [64][64][128]    FW=2 KW=4: 256 blocks x 512 thr
    tile2_kernel<64, 64, 64, 2, 4><<<dim3(64, 4), 512, 0, stream>>>(buf1, WL(4), BL(4), SL(4), buf0);
    // L6: -> [32][128][128]   FW=2 KW=4: 256 blocks x 512 thr
    tile2_kernel<64, 128, 32, 2, 4><<<dim3(32, 8), 512, 0, stream>>>(buf0, WL(5), BL(5), SL(5), buf1);
    // L7: -> [16][256][128]   FW=2 KW=4: 256 blocks x 512 thr
    tile2_kernel<128, 256, 16, 2, 4><<<dim3(16, 16), 512, 0, stream>>>(buf1, WL(6), BL(6), SL(6), buf0);
    // L8: -> [8][512][128]    FW=2 KW=8: 256 blocks x 1024 thr
    tile2_kernel<256, 512, 8, 2, 8><<<dim3(8, 32), 1024, 0, stream>>>(buf0, WL(7), BL(7), SL(7), buf1);
    // L9: -> [4][512][128]    FW=1 KW=8: 256 blocks x 512 thr
    tile2_kernel<512, 512, 4, 1, 8><<<dim3(4, 64), 512, 0, stream>>>(buf1, WL(8), BL(8), SL(8), buf0);
    // L10: -> [2][512][128]   FW=1 KW=8: 128 blocks x 512 thr
    tile2_kernel<512, 512, 2, 1, 8><<<dim3(2, 64), 512, 0, stream>>>(buf0, WL(9), BL(9), SL(9), buf1);
    // L11: -> [1][1024][128]  FW=1 KW=8: 128 blocks x 512 thr
    tile2_kernel<512, 1024, 1, 1, 8><<<dim3(1, 128), 512, 0, stream>>>(buf1, WL(10), BL(10), SL(10), buf0);

    // FC head (h = buf0, [1024][128])
    fc_logsoftmax_kernel<<<BATCH, 256, 0, stream>>>(buf0, fcW, fcb, (float*)d_out);

#undef WL
#undef BL
#undef SL
}

// Round 9
// 228.671 us; speedup vs baseline: 1.7437x; 1.7437x over previous
//
#include <hip/hip_runtime.h>
#include <math.h>

#define BATCH 128

typedef __attribute__((ext_vector_type(8))) short bf16x8;
typedef __attribute__((ext_vector_type(4))) float f32x4;

__device__ __forceinline__ unsigned short f2bf(float f) {
    unsigned u = __builtin_bit_cast(unsigned, f);
    u += 0x7FFF + ((u >> 16) & 1);          // RNE
    return (unsigned short)(u >> 16);
}
__device__ __forceinline__ float bf2f(unsigned short h) {
    unsigned u = ((unsigned)h) << 16;
    return __builtin_bit_cast(float, u);
}

// ============================================================================
// Pack: convert W3..W11 fp32 -> bf16 contiguous blob (original [3*cf][cin] layout)
// ============================================================================
struct PackArgs { const float* W[9]; int end[9]; };

__global__ __launch_bounds__(256) void pack_kernel(PackArgs pa, unsigned short* __restrict__ Wb, int total)
{
    int t = blockIdx.x * 256 + threadIdx.x;
    if (t >= total) return;
    int li = 0;
    while (t >= pa.end[li]) ++li;
    int base = (li == 0) ? 0 : pa.end[li - 1];
    Wb[t] = f2bf(pa.W[li][t - base]);
}

// ============================================================================
// Layer 1: x [128][3][2048] fp32 -> X2 [1024][128][8] bf16 (pos-major, b, f-minor)
// thread t = b*1024 + np  (np fastest -> coalesced x reads)
// ============================================================================
__global__ __launch_bounds__(256) void l1_kernel(
    const float* __restrict__ x, const float* __restrict__ W,
    const float* __restrict__ bias, const int* __restrict__ sel,
    unsigned short* __restrict__ Xout)
{
    __shared__ float wl[72];
    __shared__ float bl[24];
    int tid = threadIdx.x;
    if (tid < 72) wl[tid] = W[tid];
    if (tid >= 128 && tid < 152) bl[tid - 128] = bias[tid - 128];
    __syncthreads();

    int t  = blockIdx.x * 256 + tid;
    int np = t & 1023;
    int b  = t >> 10;
    int s0 = sel[2 * np], s1 = sel[2 * np + 1];

    const float* xb = x + (size_t)b * 6144 + 2 * np;
    float2 c0 = *(const float2*)(xb);
    float2 c1 = *(const float2*)(xb + 2048);
    float2 c2 = *(const float2*)(xb + 4096);

    unsigned short o[8];
#pragma unroll
    for (int f = 0; f < 8; ++f) {
        int r0 = f * 3 + s0, r1 = f * 3 + s1;
        float z0 = fmaf(wl[r0*3+2], c2.x, fmaf(wl[r0*3+1], c1.x, fmaf(wl[r0*3+0], c0.x, bl[r0])));
        float z1 = fmaf(wl[r1*3+2], c2.y, fmaf(wl[r1*3+1], c1.y, fmaf(wl[r1*3+0], c0.y, bl[r1])));
        o[f] = f2bf(fmaxf(fmaxf(z0, z1), 0.f));
    }
    unsigned short* dst = Xout + ((size_t)np * 128 + b) * 8;
    *(ushort4*)dst       = make_ushort4(o[0], o[1], o[2], o[3]);
    *(ushort4*)(dst + 4) = make_ushort4(o[4], o[5], o[6], o[7]);
}

// ============================================================================
// Layer 2: X2 [1024][128][8] bf16 -> X3 [512][128][32] bf16.  W fp32 via LDS.
// thread t = np*128 + b  (b fastest -> coalesced reads AND writes; sel wave-uniform)
// ============================================================================
__global__ __launch_bounds__(256) void l2_kernel(
    const unsigned short* __restrict__ Xin, const float* __restrict__ W,
    const float* __restrict__ bias, const int* __restrict__ sel,
    unsigned short* __restrict__ Xout)
{
    __shared__ float wl[768];
    __shared__ float bl[96];
    int tid = threadIdx.x;
    for (int i = tid; i < 768; i += 256) wl[i] = W[i];
    if (tid < 96) bl[tid] = bias[tid];
    __syncthreads();

    int t  = blockIdx.x * 256 + tid;
    int b  = t & 127;
    int np = t >> 7;
    int s0 = sel[2 * np], s1 = sel[2 * np + 1];

    const unsigned short* r0 = Xin + ((size_t)(2 * np) * 128 + b) * 8;
    const unsigned short* r1 = Xin + ((size_t)(2 * np + 1) * 128 + b) * 8;
    float xa[8], xb[8];
    {
        ushort4 u0 = *(const ushort4*)r0, u1 = *(const ushort4*)(r0 + 4);
        ushort4 v0 = *(const ushort4*)r1, v1 = *(const ushort4*)(r1 + 4);
        xa[0]=bf2f(u0.x); xa[1]=bf2f(u0.y); xa[2]=bf2f(u0.z); xa[3]=bf2f(u0.w);
        xa[4]=bf2f(u1.x); xa[5]=bf2f(u1.y); xa[6]=bf2f(u1.z); xa[7]=bf2f(u1.w);
        xb[0]=bf2f(v0.x); xb[1]=bf2f(v0.y); xb[2]=bf2f(v0.z); xb[3]=bf2f(v0.w);
        xb[4]=bf2f(v1.x); xb[5]=bf2f(v1.y); xb[6]=bf2f(v1.z); xb[7]=bf2f(v1.w);
    }

    unsigned short o[32];
#pragma unroll
    for (int f = 0; f < 32; ++f) {
        const float* w0 = &wl[(f * 3 + s0) * 8];
        const float* w1 = &wl[(f * 3 + s1) * 8];
        float z0 = bl[f * 3 + s0], z1 = bl[f * 3 + s1];
#pragma unroll
        for (int k = 0; k < 8; ++k) {
            z0 = fmaf(w0[k], xa[k], z0);
            z1 = fmaf(w1[k], xb[k], z1);
        }
        o[f] = f2bf(fmaxf(fmaxf(z0, z1), 0.f));
    }
    unsigned short* dst = Xout + ((size_t)np * 128 + b) * 32;
#pragma unroll
    for (int i = 0; i < 8; ++i)
        *(ushort4*)(dst + 4 * i) = make_ushort4(o[4*i], o[4*i+1], o[4*i+2], o[4*i+3]);
}

// ============================================================================
// MFMA layer (L3..L11): Xin [2*NP][128][CIN] bf16, Wb [3*CF][CIN] bf16
//  -> Xout [NP][128][CF] bf16.
// Wave task = (n, f-tile of 16*MW, b-tile of 16*NW), both positions.
// A frag: W[f0+mi*16+c][k0 + q*8 .. +8]  (one dwordx4 per frag)
// B frag: X[2n+p][b0+ni*16+c][k0 + q*8 .. +8]  (one dwordx4 per frag)
// D: col(b)=lane&15, row(f)=q*4+reg  [verified m89]
// Epilogue: bias + relu + pairwise max fused; bf16 store.
// ============================================================================
template<int CIN, int CF, int NP, int MW, int NW>
__global__ __launch_bounds__(256) void mfma_kernel(
    const unsigned short* __restrict__ Xin,
    const unsigned short* __restrict__ Wb,
    const float* __restrict__ bias,
    const int*   __restrict__ sel,
    unsigned short* __restrict__ Xout)
{
    constexpr int FT = CF / (16 * MW);
    constexpr int BT = 128 / (16 * NW);

    const int wid  = threadIdx.x >> 6;
    const int lane = threadIdx.x & 63;
    const int task = blockIdx.x * 4 + wid;
    const int bi = task % BT;
    const int fi = (task / BT) % FT;
    const int n  = task / (BT * FT);

    const int c = lane & 15;
    const int q = lane >> 4;
    const int s0 = __builtin_amdgcn_readfirstlane(sel[2 * n]);
    const int s1 = __builtin_amdgcn_readfirstlane(sel[2 * n + 1]);

    const int f0 = fi * 16 * MW;
    const int b0 = bi * 16 * NW;

    const unsigned short* ap[2][MW];
    const unsigned short* bp[2][NW];
#pragma unroll
    for (int p = 0; p < 2; ++p) {
        int s = p ? s1 : s0;
#pragma unroll
        for (int mi = 0; mi < MW; ++mi)
            ap[p][mi] = Wb + (size_t)((f0 + mi * 16 + c) * 3 + s) * CIN + q * 8;
#pragma unroll
        for (int ni = 0; ni < NW; ++ni)
            bp[p][ni] = Xin + ((size_t)(2 * n + p) * 128 + b0 + ni * 16 + c) * CIN + q * 8;
    }

    f32x4 acc[2][MW][NW];
#pragma unroll
    for (int p = 0; p < 2; ++p)
#pragma unroll
        for (int mi = 0; mi < MW; ++mi)
#pragma unroll
            for (int ni = 0; ni < NW; ++ni)
                acc[p][mi][ni] = (f32x4){0.f, 0.f, 0.f, 0.f};

#pragma unroll 2
    for (int k = 0; k < CIN; k += 32) {
        bf16x8 A[2][MW], B[2][NW];
#pragma unroll
        for (int p = 0; p < 2; ++p) {
#pragma unroll
            for (int mi = 0; mi < MW; ++mi)
                A[p][mi] = __builtin_bit_cast(bf16x8, *(const float4*)(const void*)(ap[p][mi] + k));
#pragma unroll
            for (int ni = 0; ni < NW; ++ni)
                B[p][ni] = __builtin_bit_cast(bf16x8, *(const float4*)(const void*)(bp[p][ni] + k));
        }
#pragma unroll
        for (int p = 0; p < 2; ++p)
#pragma unroll
            for (int mi = 0; mi < MW; ++mi)
#pragma unroll
                for (int ni = 0; ni < NW; ++ni)
                    acc[p][mi][ni] = __builtin_amdgcn_mfma_f32_16x16x32_bf16(
                        A[p][mi], B[p][ni], acc[p][mi][ni], 0, 0, 0);
    }

    // epilogue
#pragma unroll
    for (int mi = 0; mi < MW; ++mi) {
        int fbase = f0 + mi * 16 + q * 4;
        float bi0[4], bi1[4];
#pragma unroll
        for (int r = 0; r < 4; ++r) {
            bi0[r] = bias[(fbase + r) * 3 + s0];
            bi1[r] = bias[(fbase + r) * 3 + s1];
        }
#pragma unroll
        for (int ni = 0; ni < NW; ++ni) {
            int b = b0 + ni * 16 + c;
            unsigned short o[4];
#pragma unroll
            for (int r = 0; r < 4; ++r) {
                float v = fmaxf(fmaxf(acc[0][mi][ni][r] + bi0[r],
                                      acc[1][mi][ni][r] + bi1[r]), 0.f);
                o[r] = f2bf(v);
            }
            *(ushort4*)(Xout + ((size_t)n * 128 + b) * CF + fbase) =
                make_ushort4(o[0], o[1], o[2], o[3]);
        }
    }
}

// ============================================================================
// FC head: h bf16 [128][1024]; out [128][16] fp32 log-softmax
// ============================================================================
__global__ __launch_bounds__(256) void fc_logsoftmax_kernel(
    const unsigned short* __restrict__ h, const float* __restrict__ fcW,
    const float* __restrict__ fcb, float* __restrict__ out)
{
    int b   = blockIdx.x;
    int tid = threadIdx.x;
    int k     = tid & 15;
    int chunk = tid >> 4;

    const float* __restrict__ wk = fcW + (size_t)k * 1024;
    const unsigned short* hb = h + (size_t)b * 1024;

    float partial = 0.0f;
    int j0 = chunk * 64;
#pragma unroll 8
    for (int j = 0; j < 64; ++j)
        partial = fmaf(bf2f(hb[j0 + j]), wk[j0 + j], partial);

    __shared__ float red[16][17];
    red[chunk][k] = partial;
    __syncthreads();

    __shared__ float logits[16];
    if (tid < 16) {
        float s = fcb[tid];
#pragma unroll
        for (int c = 0; c < 16; ++c) s += red[c][tid];
        logits[tid] = s;
    }
    __syncthreads();

    if (tid < 16) {
        float mx = -INFINITY;
#pragma unroll
        for (int kk = 0; kk < 16; ++kk) mx = fmaxf(mx, logits[kk]);
        float se = 0.0f;
#pragma unroll
        for (int kk = 0; kk < 16; ++kk) se += expf(logits[kk] - mx);
        out[b * 16 + tid] = logits[tid] - mx - logf(se);
    }
}

// ============================================================================
extern "C" void kernel_launch(void* const* d_in, const int* in_sizes, int n_in,
                              void* d_out, int out_size, void* d_ws, size_t ws_size,
                              hipStream_t stream)
{
    const float* x   = (const float*)d_in[0];
    const float* fcW = (const float*)d_in[34];
    const float* fcb = (const float*)d_in[35];

#define WL(i) (const float*)d_in[1 + 3 * (i)]
#define BL(i) (const float*)d_in[2 + 3 * (i)]
#define SL(i) (const int*)  d_in[3 + 3 * (i)]

    unsigned short* buf0 = (unsigned short*)d_ws;                  // 4 MB (2M bf16)
    unsigned short* buf1 = buf0 + 2u * 1024u * 1024u;              // 4 MB
    unsigned short* Wb   = buf1 + 2u * 1024u * 1024u;              // 7.4 MB packed W

    // ---- pack W for layers 3..11 to bf16 ----
    // elems: L3 6144, L4 12288, L5 12288, L6 24576, L7 98304, L8 393216,
    //        L9 786432, L10 786432, L11 1572864  (total 3,692,544)
    static const int welems[9] = {6144, 12288, 12288, 24576, 98304, 393216, 786432, 786432, 1572864};
    PackArgs pa;
    int accum = 0, woff[9];
    for (int i = 0; i < 9; ++i) {
        pa.W[i] = WL(i + 2);
        woff[i] = accum;
        accum += welems[i];
        pa.end[i] = accum;
    }
    pack_kernel<<<(accum + 255) / 256, 256, 0, stream>>>(pa, Wb, accum);

    // ---- L1, L2 (VALU) ----
    l1_kernel<<<512, 256, 0, stream>>>(x, WL(0), BL(0), SL(0), buf0);
    l2_kernel<<<256, 256, 0, stream>>>(buf0, WL(1), BL(1), SL(1), buf1);

    // ---- L3..L11 (MFMA) ----
    mfma_kernel<32, 64, 256, 2, 2><<<512, 256, 0, stream>>>(buf1, Wb + woff[0], BL(2), SL(2), buf0);
    mfma_kernel<64, 64, 128, 2, 2><<<256, 256, 0, stream>>>(buf0, Wb + woff[1], BL(3), SL(3), buf1);
    mfma_kernel<64, 64, 64, 2, 2><<<128, 256, 0, stream>>>(buf1, Wb + woff[2], BL(4), SL(4), buf0);
    mfma_kernel<64, 128, 32, 2, 2><<<128, 256, 0, stream>>>(buf0, Wb + woff[3], BL(5), SL(5), buf1);
    mfma_kernel<128, 256, 16, 2, 2><<<128, 256, 0, stream>>>(buf1, Wb + woff[4], BL(6), SL(6), buf0);
    mfma_kernel<256, 512, 8, 2, 2><<<128, 256, 0, stream>>>(buf0, Wb + woff[5], BL(7), SL(7), buf1);
    mfma_kernel<512, 512, 4, 1, 2><<<128, 256, 0, stream>>>(buf1, Wb + woff[6], BL(8), SL(8), buf0);
    mfma_kernel<512, 512, 2, 1, 2><<<64, 256, 0, stream>>>(buf0, Wb + woff[7], BL(9), SL(9), buf1);
    mfma_kernel<512, 1024, 1, 1, 2><<<64, 256, 0, stream>>>(buf1, Wb + woff[8], BL(10), SL(10), buf0);

    // ---- FC head ----
    fc_logsoftmax_kernel<<<BATCH, 256, 0, stream>>>(buf0, fcW, fcb, (float*)d_out);

#undef WL
#undef BL
#undef SL
}